// Round 10
// baseline (207.738 us; speedup 1.0000x reference)
//
#include <hip/hip_runtime.h>
#include <math.h>

#define H 128
#define PART_EDGES 4096
#define SORT_LDS 4096

typedef __bf16 bf16x8 __attribute__((ext_vector_type(8)));
typedef float f32x4 __attribute__((ext_vector_type(4)));

static __device__ __forceinline__ unsigned short f2bf(float f) {
    unsigned u = __float_as_uint(f);
    unsigned r = 0x7fffu + ((u >> 16) & 1u);
    return (unsigned short)((u + r) >> 16);
}
static __device__ __forceinline__ float bflo(unsigned w) {
    return __uint_as_float(w << 16);
}
static __device__ __forceinline__ float bfhi(unsigned w) {
    return __uint_as_float(w & 0xffff0000u);
}

// per-block LDS bucket histogram -> padded global bcnt (stride 16 ints = 64B)
__global__ __launch_bounds__(256) void k_bhist(const int* __restrict__ dst,
                                               int* __restrict__ bcnt_pad,
                                               int E, int NBUK) {
    __shared__ int lh[1024];
    int t = threadIdx.x;
    for (int i = t; i < 1024; i += 256) lh[i] = 0;
    __syncthreads();
    int e0 = blockIdx.x * PART_EDGES;
    int e1 = min(e0 + PART_EDGES, E);
    for (int e = e0 + t; e < e1; e += 256) atomicAdd(&lh[dst[e] >> 7], 1);
    __syncthreads();
    for (int i = t; i < NBUK; i += 256) {
        int h = lh[i];
        if (h) atomicAdd(&bcnt_pad[i * 16], h);
    }
}

// parallel single-block exclusive scan of bucket counts (chunked, carry LDS)
__global__ __launch_bounds__(1024) void k_bscan(const int* __restrict__ bcnt_pad,
                                                int* __restrict__ boff,
                                                int* __restrict__ bcur,
                                                int* __restrict__ rowp,
                                                int NBUK, int N, int E) {
    __shared__ int tmp[1024];
    __shared__ int carry;
    int t = threadIdx.x;
    if (t == 0) carry = 0;
    __syncthreads();
    for (int base = 0; base < NBUK; base += 1024) {
        int i = base + t;
        int v = (i < NBUK) ? bcnt_pad[i * 16] : 0;
        tmp[t] = v;
        __syncthreads();
#pragma unroll
        for (int off = 1; off < 1024; off <<= 1) {
            int a = (t >= off) ? tmp[t - off] : 0;
            __syncthreads();
            tmp[t] += a;
            __syncthreads();
        }
        int excl = carry + tmp[t] - v;
        if (i < NBUK) { boff[i] = excl; bcur[i] = excl; }
        __syncthreads();
        if (t == 1023) carry += tmp[1023];
        __syncthreads();
    }
    if (t == 0) { boff[NBUK] = carry; rowp[N] = E; }
}

// --------------------------------------------------- W transpose to bf16 ----
__global__ void k_wt(const float* __restrict__ W, unsigned short* __restrict__ Wt) {
    int t = blockIdx.x * 256 + threadIdx.x;   // 16384 threads
    int j = t >> 7, k = t & 127;
    Wt[(size_t)j * H + k] = f2bf(W[(size_t)k * H + j]);
}

// ------------------- x pre-scale: word w = bf16 pair (feat 2w, 2w+1) --------
__global__ void k_xb(const float* __restrict__ x, const float* __restrict__ dinv,
                     unsigned* __restrict__ xb2, int N) {
    int t = blockIdx.x * 256 + threadIdx.x;   // N*32 threads
    if (t >= N * 32) return;
    int n = t >> 5;
    float s = dinv[n];
    float4 v = ((const float4*)x)[t];
    uint2 o;
    o.x = (unsigned)f2bf(v.x * s) | ((unsigned)f2bf(v.y * s) << 16);
    o.y = (unsigned)f2bf(v.z * s) | ((unsigned)f2bf(v.w * s) << 16);
    ((uint2*)xb2)[t] = o;
}

// -------------------------------------------- bucket partition of edges -----
// record = src | (dst&127)<<17 ; grouped by bucket (dst>>7)
__global__ __launch_bounds__(256) void k_part(const int* __restrict__ ei,
                                              int* __restrict__ bcur,
                                              unsigned* __restrict__ pair, int E) {
    __shared__ int hist[1024];
    __shared__ int base[1024];
    int t = threadIdx.x;
    for (int i = t; i < 1024; i += 256) hist[i] = 0;
    __syncthreads();
    int e0 = blockIdx.x * PART_EDGES;
    int e1 = min(e0 + PART_EDGES, E);
    for (int e = e0 + t; e < e1; e += 256) {
        int d = ei[E + e];
        atomicAdd(&hist[d >> 7], 1);
    }
    __syncthreads();
    for (int i = t; i < 1024; i += 256) {
        int h = hist[i];
        base[i] = h ? atomicAdd(&bcur[i], h) : 0;
        hist[i] = 0;  // reuse as local cursor
    }
    __syncthreads();
    for (int e = e0 + t; e < e1; e += 256) {
        int s = ei[e];
        int d = ei[E + e];
        int b = d >> 7;
        int r = atomicAdd(&hist[b], 1);
        pair[base[b] + r] = (unsigned)s | ((unsigned)(d & 127) << 17);
    }
}

// --------------- bucket-local counting sort -> ssrc, rowp, dinv -------------
__global__ __launch_bounds__(256) void k_sort(const unsigned* __restrict__ pair,
                                              const int* __restrict__ boff,
                                              int* __restrict__ rowp,
                                              int* __restrict__ ssrc,
                                              float* __restrict__ dinv, int N) {
    __shared__ int hist[128];
    __shared__ int lofs[128];
    __shared__ int cur[128];
    __shared__ int sl[SORT_LDS];
    int b = blockIdx.x;
    int t = threadIdx.x;
    int lo = boff[b], hi = boff[b + 1];
    int cntE = hi - lo;
    if (t < 128) hist[t] = 0;
    __syncthreads();
    for (int i = t; i < cntE; i += 256) {
        unsigned w = pair[lo + i];
        atomicAdd(&hist[w >> 17], 1);
    }
    __syncthreads();
    int n0 = b << 7;
    if (t < 128 && n0 + t < N) dinv[n0 + t] = rsqrtf((float)(hist[t] + 1));
    if (t == 0) {
        int run = 0;
        for (int d = 0; d < 128; ++d) { lofs[d] = run; cur[d] = run; run += hist[d]; }
    }
    __syncthreads();
    if (t < 128 && n0 + t < N) rowp[n0 + t] = lo + lofs[t];
    for (int i = t; i < cntE; i += 256) {
        unsigned w = pair[lo + i];
        int d = w >> 17;
        int s = (int)(w & 0x1FFFF);
        int pos = atomicAdd(&cur[d], 1);
        if (pos < SORT_LDS) sl[pos] = s;
        else ssrc[lo + pos] = s;   // statistically never; correctness fallback
    }
    __syncthreads();
    int lim = min(cntE, SORT_LDS);
    for (int i = t; i < lim; i += 256) ssrc[lo + i] = sl[i];
}

// ------------- FUSED: gather aggregate -> MFMA GEMM + GELU + LN -------------
// one block per bucket of 128 nodes; 512 threads = 8 waves.
// phase 1: wave wv gathers nodes n0+wv*16..+15 (round-9 k_agg inner loop),
//          writes bf16 rows into a 32KB XOR-swizzled LDS A-tile.
// phase 2: per-wave 16x128 MFMA GEMM; A from LDS, B (Wt) from global
//          (32KB, L1/L2-resident); bias+erf-GELU+LayerNorm epilogue to d_out.
__global__ __launch_bounds__(512) void k_fused(const unsigned* __restrict__ xb2,
                                               const int* __restrict__ rowp,
                                               const int* __restrict__ ssrc,
                                               const float* __restrict__ dinv,
                                               const unsigned short* __restrict__ Wt,
                                               const float* __restrict__ bias,
                                               const float* __restrict__ gamma,
                                               const float* __restrict__ beta,
                                               float* __restrict__ outp, int N) {
    __shared__ unsigned char Atile[128 * 256];  // 32 KB

    const int wv   = threadIdx.x >> 6;
    const int lane = threadIdx.x & 63;
    const int grp  = lane >> 4;
    const int sub  = lane & 15;
    const int n0   = blockIdx.x << 7;

    // ---------------- phase 1: gather ----------------
    for (int i = 0; i < 16; ++i) {
        int lr = wv * 16 + i;
        int n  = n0 + lr;
        unsigned bo = ((unsigned)(lr * 256 + sub * 16)) ^ (((unsigned)lr & 7u) << 4);
        if (n >= N) {
            if (grp == 0) *(uint4*)(Atile + bo) = make_uint4(0u, 0u, 0u, 0u);
            continue;  // wave-uniform (n depends only on wv,i)
        }
        int lo = __builtin_amdgcn_readfirstlane(rowp[n]);
        int hi = __builtin_amdgcn_readfirstlane(rowp[n + 1]);

        float acc[8];
#pragma unroll
        for (int k2 = 0; k2 < 8; ++k2) acc[k2] = 0.f;

        if (grp == 0) {  // self term once
            uint4 sw = ((const uint4*)(xb2 + (size_t)n * 64))[sub];
            acc[0] = bflo(sw.x); acc[1] = bfhi(sw.x);
            acc[2] = bflo(sw.y); acc[3] = bfhi(sw.y);
            acc[4] = bflo(sw.z); acc[5] = bfhi(sw.z);
            acc[6] = bflo(sw.w); acc[7] = bfhi(sw.w);
        }

        for (int base = lo; base < hi; base += 64) {
            int take = hi - base; if (take > 64) take = 64;   // wave-uniform
            int sv = ssrc[base + (lane < take ? lane : take - 1)];
            int nIter = (take + 7) >> 3;                      // wave-uniform
            for (int it = 0; it < nIter; ++it) {
                int p1 = (it << 3) + grp;
                int p2 = p1 + 4;
                int q1 = (p1 < take) ? p1 : take - 1;
                int q2 = (p2 < take) ? p2 : take - 1;
                float v1 = (p1 < take) ? 1.0f : 0.0f;
                float v2 = (p2 < take) ? 1.0f : 0.0f;
                int s1 = __builtin_amdgcn_ds_bpermute(q1 << 2, sv);
                int s2 = __builtin_amdgcn_ds_bpermute(q2 << 2, sv);
                uint4 w1 = ((const uint4*)(xb2 + (size_t)s1 * 64))[sub];
                uint4 w2 = ((const uint4*)(xb2 + (size_t)s2 * 64))[sub];
                acc[0] = fmaf(bflo(w1.x), v1, acc[0]);
                acc[1] = fmaf(bfhi(w1.x), v1, acc[1]);
                acc[2] = fmaf(bflo(w1.y), v1, acc[2]);
                acc[3] = fmaf(bfhi(w1.y), v1, acc[3]);
                acc[4] = fmaf(bflo(w1.z), v1, acc[4]);
                acc[5] = fmaf(bfhi(w1.z), v1, acc[5]);
                acc[6] = fmaf(bflo(w1.w), v1, acc[6]);
                acc[7] = fmaf(bfhi(w1.w), v1, acc[7]);
                acc[0] = fmaf(bflo(w2.x), v2, acc[0]);
                acc[1] = fmaf(bfhi(w2.x), v2, acc[1]);
                acc[2] = fmaf(bflo(w2.y), v2, acc[2]);
                acc[3] = fmaf(bfhi(w2.y), v2, acc[3]);
                acc[4] = fmaf(bflo(w2.z), v2, acc[4]);
                acc[5] = fmaf(bfhi(w2.z), v2, acc[5]);
                acc[6] = fmaf(bflo(w2.w), v2, acc[6]);
                acc[7] = fmaf(bfhi(w2.w), v2, acc[7]);
            }
        }
#pragma unroll
        for (int k2 = 0; k2 < 8; ++k2) {
            acc[k2] += __shfl_xor(acc[k2], 16, 64);
            acc[k2] += __shfl_xor(acc[k2], 32, 64);
        }
        if (grp == 0) {
            float dn = dinv[n];
            uint4 o;
            o.x = (unsigned)f2bf(acc[0] * dn) | ((unsigned)f2bf(acc[1] * dn) << 16);
            o.y = (unsigned)f2bf(acc[2] * dn) | ((unsigned)f2bf(acc[3] * dn) << 16);
            o.z = (unsigned)f2bf(acc[4] * dn) | ((unsigned)f2bf(acc[5] * dn) << 16);
            o.w = (unsigned)f2bf(acc[6] * dn) | ((unsigned)f2bf(acc[7] * dn) << 16);
            *(uint4*)(Atile + bo) = o;
        }
    }
    __syncthreads();

    // ---------------- phase 2: GEMM + epilogue ----------------
    const int g = grp;
    const int c = sub;
    const int r0 = n0 + wv * 16;

    float bc[8], gc[8], bec[8];
#pragma unroll
    for (int ct = 0; ct < 8; ++ct) {
        int col = ct * 16 + c;
        bc[ct]  = bias[col];
        gc[ct]  = gamma[col];
        bec[ct] = beta[col];
    }

    f32x4 acc2[8];
#pragma unroll
    for (int ct = 0; ct < 8; ++ct) acc2[ct] = (f32x4){0.f, 0.f, 0.f, 0.f};

#pragma unroll
    for (int ks = 0; ks < 4; ++ks) {
        int lr = wv * 16 + c;   // A row (local)
        unsigned bo = ((unsigned)(lr * 256 + ks * 64 + g * 16)) ^ (((unsigned)lr & 7u) << 4);
        bf16x8 af = *(const bf16x8*)(Atile + bo);   // ds_read_b128
#pragma unroll
        for (int ct = 0; ct < 8; ++ct) {
            int j = ct * 16 + c;
            bf16x8 bf = *(const bf16x8*)(Wt + (size_t)j * H + ks * 32 + g * 8);
            acc2[ct] = __builtin_amdgcn_mfma_f32_16x16x32_bf16(af, bf, acc2[ct], 0, 0, 0);
        }
    }

#pragma unroll
    for (int q = 0; q < 4; ++q) {
        int row = r0 + g * 4 + q;
        float v[8];
        float s = 0.f, sq = 0.f;
#pragma unroll
        for (int ct = 0; ct < 8; ++ct) {
            float t = acc2[ct][q] + bc[ct];
            t = 0.5f * t * (1.0f + erff(t * 0.70710678118654752f));
            v[ct] = t;
            s += t;
            sq += t * t;
        }
#pragma unroll
        for (int off = 8; off > 0; off >>= 1) {
            s  += __shfl_xor(s,  off, 64);
            sq += __shfl_xor(sq, off, 64);
        }
        float mu  = s * (1.0f / H);
        float var = sq * (1.0f / H) - mu * mu;
        float rs  = rsqrtf(var + 1e-5f);
        if (row < N) {
            float* op = outp + (size_t)row * H;
#pragma unroll
            for (int ct = 0; ct < 8; ++ct) {
                op[ct * 16 + c] = (v[ct] - mu) * rs * gc[ct] + bec[ct];
            }
        }
    }
}

// ---------------------------------------------------------------- launch ----
extern "C" void kernel_launch(void* const* d_in, const int* in_sizes, int n_in,
                              void* d_out, int out_size, void* d_ws, size_t ws_size,
                              hipStream_t stream) {
    const float* x     = (const float*)d_in[0];
    const int*   ei    = (const int*)d_in[1];
    const float* W     = (const float*)d_in[2];
    const float* b     = (const float*)d_in[3];
    const float* gamma = (const float*)d_in[4];
    const float* beta  = (const float*)d_in[5];
    float* out = (float*)d_out;

    const int N = in_sizes[0] / H;
    const int E = in_sizes[1] / 2;
    const int NBUK = (N + 127) / 128;

    // workspace layout (256 B aligned between arrays)
    char* w = (char*)d_ws;
    auto alloc = [&](size_t bytes) {
        char* p = w;
        w += (bytes + 255) & ~(size_t)255;
        return p;
    };
    float* dinv     = (float*)alloc((size_t)N * 4);
    int*   bcnt_pad = (int*)alloc((size_t)NBUK * 16 * 4);  // 64B-padded counters
    int*   boff     = (int*)alloc((size_t)(NBUK + 1) * 4);
    int*   bcur     = (int*)alloc((size_t)NBUK * 4);
    int*   rowp     = (int*)alloc((size_t)(N + 1) * 4);
    int*   ssrc     = (int*)alloc((size_t)E * 4);
    unsigned short* Wt = (unsigned short*)alloc((size_t)H * H * 2);
    unsigned* xb2   = (unsigned*)alloc((size_t)N * 64 * 4);  // bf16 x*dinv (ws!)

    // d_out upper part stages pair records (consumed by k_sort before k_fused
    // writes d_out).
    unsigned* pair = (unsigned*)d_out + (size_t)N * 64;  // E u32

    k_wt   <<<(H * H) / 256, 256, 0, stream>>>(W, Wt);

    hipMemsetAsync(bcnt_pad, 0, (size_t)NBUK * 16 * 4, stream);
    k_bhist<<<(E + PART_EDGES - 1) / PART_EDGES, 256, 0, stream>>>(ei + E, bcnt_pad, E, NBUK);
    k_bscan<<<1, 1024, 0, stream>>>(bcnt_pad, boff, bcur, rowp, NBUK, N, E);
    k_part <<<(E + PART_EDGES - 1) / PART_EDGES, 256, 0, stream>>>(ei, bcur, pair, E);
    k_sort <<<NBUK, 256, 0, stream>>>(pair, boff, rowp, ssrc, dinv, N);
    k_xb   <<<(N * 32 + 255) / 256, 256, 0, stream>>>(x, dinv, xb2, N);

    k_fused<<<NBUK, 512, 0, stream>>>(xb2, rowp, ssrc, dinv, Wt,
                                      b, gamma, beta, out, N);
}

// Round 11
// 184.032 us; speedup vs baseline: 1.1288x; 1.1288x over previous
//
#include <hip/hip_runtime.h>
#include <math.h>

#define H 128
#define PART_EDGES 4096
#define SORT_LDS 4096

typedef __bf16 bf16x8 __attribute__((ext_vector_type(8)));
typedef float f32x4 __attribute__((ext_vector_type(4)));

static __device__ __forceinline__ unsigned short f2bf(float f) {
    unsigned u = __float_as_uint(f);
    unsigned r = 0x7fffu + ((u >> 16) & 1u);
    return (unsigned short)((u + r) >> 16);
}
static __device__ __forceinline__ float bflo(unsigned w) {
    return __uint_as_float(w << 16);
}
static __device__ __forceinline__ float bfhi(unsigned w) {
    return __uint_as_float(w & 0xffff0000u);
}

// per-block LDS bucket histogram -> padded global bcnt (stride 16 ints = 64B)
__global__ __launch_bounds__(256) void k_bhist(const int* __restrict__ dst,
                                               int* __restrict__ bcnt_pad,
                                               int E, int NBUK) {
    __shared__ int lh[1024];
    int t = threadIdx.x;
    for (int i = t; i < 1024; i += 256) lh[i] = 0;
    __syncthreads();
    int e0 = blockIdx.x * PART_EDGES;
    int e1 = min(e0 + PART_EDGES, E);
    for (int e = e0 + t; e < e1; e += 256) atomicAdd(&lh[dst[e] >> 7], 1);
    __syncthreads();
    for (int i = t; i < NBUK; i += 256) {
        int h = lh[i];
        if (h) atomicAdd(&bcnt_pad[i * 16], h);
    }
}

// parallel single-block exclusive scan of bucket counts (chunked, carry LDS)
__global__ __launch_bounds__(1024) void k_bscan(const int* __restrict__ bcnt_pad,
                                                int* __restrict__ boff,
                                                int* __restrict__ bcur,
                                                int* __restrict__ rowp,
                                                int NBUK, int N, int E) {
    __shared__ int tmp[1024];
    __shared__ int carry;
    int t = threadIdx.x;
    if (t == 0) carry = 0;
    __syncthreads();
    for (int base = 0; base < NBUK; base += 1024) {
        int i = base + t;
        int v = (i < NBUK) ? bcnt_pad[i * 16] : 0;
        tmp[t] = v;
        __syncthreads();
#pragma unroll
        for (int off = 1; off < 1024; off <<= 1) {
            int a = (t >= off) ? tmp[t - off] : 0;
            __syncthreads();
            tmp[t] += a;
            __syncthreads();
        }
        int excl = carry + tmp[t] - v;
        if (i < NBUK) { boff[i] = excl; bcur[i] = excl; }
        __syncthreads();
        if (t == 1023) carry += tmp[1023];
        __syncthreads();
    }
    if (t == 0) { boff[NBUK] = carry; rowp[N] = E; }
}

// --------------------------------------------------- W transpose to bf16 ----
__global__ void k_wt(const float* __restrict__ W, unsigned short* __restrict__ Wt) {
    int t = blockIdx.x * 256 + threadIdx.x;   // 16384 threads
    int j = t >> 7, k = t & 127;
    Wt[(size_t)j * H + k] = f2bf(W[(size_t)k * H + j]);
}

// ------------------- x pre-scale: word w = bf16 pair (feat 2w, 2w+1) --------
__global__ void k_xb(const float* __restrict__ x, const float* __restrict__ dinv,
                     unsigned* __restrict__ xb2, int N) {
    int t = blockIdx.x * 256 + threadIdx.x;   // N*32 threads
    if (t >= N * 32) return;
    int n = t >> 5;
    float s = dinv[n];
    float4 v = ((const float4*)x)[t];
    uint2 o;
    o.x = (unsigned)f2bf(v.x * s) | ((unsigned)f2bf(v.y * s) << 16);
    o.y = (unsigned)f2bf(v.z * s) | ((unsigned)f2bf(v.w * s) << 16);
    ((uint2*)xb2)[t] = o;
}

// -------------------------------------------- bucket partition of edges -----
// record = src | (dst&127)<<17 ; grouped by bucket (dst>>7)
__global__ __launch_bounds__(256) void k_part(const int* __restrict__ ei,
                                              int* __restrict__ bcur,
                                              unsigned* __restrict__ pair, int E) {
    __shared__ int hist[1024];
    __shared__ int base[1024];
    int t = threadIdx.x;
    for (int i = t; i < 1024; i += 256) hist[i] = 0;
    __syncthreads();
    int e0 = blockIdx.x * PART_EDGES;
    int e1 = min(e0 + PART_EDGES, E);
    for (int e = e0 + t; e < e1; e += 256) {
        int d = ei[E + e];
        atomicAdd(&hist[d >> 7], 1);
    }
    __syncthreads();
    for (int i = t; i < 1024; i += 256) {
        int h = hist[i];
        base[i] = h ? atomicAdd(&bcur[i], h) : 0;
        hist[i] = 0;  // reuse as local cursor
    }
    __syncthreads();
    for (int e = e0 + t; e < e1; e += 256) {
        int s = ei[e];
        int d = ei[E + e];
        int b = d >> 7;
        int r = atomicAdd(&hist[b], 1);
        pair[base[b] + r] = (unsigned)s | ((unsigned)(d & 127) << 17);
    }
}

// --------------- bucket-local counting sort -> ssrc, rowp, dinv -------------
__global__ __launch_bounds__(256) void k_sort(const unsigned* __restrict__ pair,
                                              const int* __restrict__ boff,
                                              int* __restrict__ rowp,
                                              int* __restrict__ ssrc,
                                              float* __restrict__ dinv, int N) {
    __shared__ int hist[128];
    __shared__ int lofs[128];
    __shared__ int cur[128];
    __shared__ int sl[SORT_LDS];
    int b = blockIdx.x;
    int t = threadIdx.x;
    int lo = boff[b], hi = boff[b + 1];
    int cntE = hi - lo;
    if (t < 128) hist[t] = 0;
    __syncthreads();
    for (int i = t; i < cntE; i += 256) {
        unsigned w = pair[lo + i];
        atomicAdd(&hist[w >> 17], 1);
    }
    __syncthreads();
    int n0 = b << 7;
    if (t < 128 && n0 + t < N) dinv[n0 + t] = rsqrtf((float)(hist[t] + 1));
    if (t == 0) {
        int run = 0;
        for (int d = 0; d < 128; ++d) { lofs[d] = run; cur[d] = run; run += hist[d]; }
    }
    __syncthreads();
    if (t < 128 && n0 + t < N) rowp[n0 + t] = lo + lofs[t];
    for (int i = t; i < cntE; i += 256) {
        unsigned w = pair[lo + i];
        int d = w >> 17;
        int s = (int)(w & 0x1FFFF);
        int pos = atomicAdd(&cur[d], 1);
        if (pos < SORT_LDS) sl[pos] = s;
        else ssrc[lo + pos] = s;   // statistically never; correctness fallback
    }
    __syncthreads();
    int lim = min(cntE, SORT_LDS);
    for (int i = t; i < lim; i += 256) ssrc[lo + i] = sl[i];
}

// ------------------------------------------------------ gather aggregate ----
// wave per node; 16 lanes per edge-row (uint4 = 16B/lane). Full 8-edge
// iterations run mask-free; the single partial tail iteration predicates the
// loads+FMAs under exec (masked lanes issue NO memory requests -> no wasted
// gather bytes). ds_bpermute always executes with all 64 lanes active.
__global__ __launch_bounds__(256) void k_agg(const unsigned* __restrict__ xb2,
                                             const int* __restrict__ rowp,
                                             const int* __restrict__ ssrc,
                                             const float* __restrict__ dinv,
                                             unsigned* __restrict__ aggb2, int N) {
    int n = blockIdx.x * 4 + (threadIdx.x >> 6);
    if (n >= N) return;
    int lane = threadIdx.x & 63;
    int grp  = lane >> 4;     // 0..3
    int sub  = lane & 15;     // 0..15

    int lo = __builtin_amdgcn_readfirstlane(rowp[n]);
    int hi = __builtin_amdgcn_readfirstlane(rowp[n + 1]);
    float dn = dinv[n];

    float acc[8];
#pragma unroll
    for (int i = 0; i < 8; ++i) acc[i] = 0.f;

    // self term, added once (group 0 only)
    if (grp == 0) {
        uint4 sw = ((const uint4*)(xb2 + (size_t)n * 64))[sub];
        acc[0] = bflo(sw.x); acc[1] = bfhi(sw.x);
        acc[2] = bflo(sw.y); acc[3] = bfhi(sw.y);
        acc[4] = bflo(sw.z); acc[5] = bfhi(sw.z);
        acc[6] = bflo(sw.w); acc[7] = bfhi(sw.w);
    }

    for (int base = lo; base < hi; base += 64) {
        int take = hi - base; if (take > 64) take = 64;   // wave-uniform
        int sv = ssrc[base + (lane < take ? lane : take - 1)];

        int nFull = take >> 3;                            // wave-uniform
        for (int it = 0; it < nFull; ++it) {
            int p1 = (it << 3) + grp;
            int p2 = p1 + 4;
            int s1 = __builtin_amdgcn_ds_bpermute(p1 << 2, sv);
            int s2 = __builtin_amdgcn_ds_bpermute(p2 << 2, sv);
            uint4 w1 = ((const uint4*)(xb2 + (size_t)s1 * 64))[sub];
            uint4 w2 = ((const uint4*)(xb2 + (size_t)s2 * 64))[sub];
            acc[0] += bflo(w1.x); acc[1] += bfhi(w1.x);
            acc[2] += bflo(w1.y); acc[3] += bfhi(w1.y);
            acc[4] += bflo(w1.z); acc[5] += bfhi(w1.z);
            acc[6] += bflo(w1.w); acc[7] += bfhi(w1.w);
            acc[0] += bflo(w2.x); acc[1] += bfhi(w2.x);
            acc[2] += bflo(w2.y); acc[3] += bfhi(w2.y);
            acc[4] += bflo(w2.z); acc[5] += bfhi(w2.z);
            acc[6] += bflo(w2.w); acc[7] += bfhi(w2.w);
        }
        if (take & 7) {                                    // wave-uniform tail
            int p1 = (nFull << 3) + grp;
            int p2 = p1 + 4;
            int q1 = (p1 < take) ? p1 : take - 1;
            int q2 = (p2 < take) ? p2 : take - 1;
            // bpermute with ALL lanes active (sources always valid)
            int s1 = __builtin_amdgcn_ds_bpermute(q1 << 2, sv);
            int s2 = __builtin_amdgcn_ds_bpermute(q2 << 2, sv);
            if (p1 < take) {
                uint4 w1 = ((const uint4*)(xb2 + (size_t)s1 * 64))[sub];
                acc[0] += bflo(w1.x); acc[1] += bfhi(w1.x);
                acc[2] += bflo(w1.y); acc[3] += bfhi(w1.y);
                acc[4] += bflo(w1.z); acc[5] += bfhi(w1.z);
                acc[6] += bflo(w1.w); acc[7] += bfhi(w1.w);
            }
            if (p2 < take) {
                uint4 w2 = ((const uint4*)(xb2 + (size_t)s2 * 64))[sub];
                acc[0] += bflo(w2.x); acc[1] += bfhi(w2.x);
                acc[2] += bflo(w2.y); acc[3] += bfhi(w2.y);
                acc[4] += bflo(w2.z); acc[5] += bfhi(w2.z);
                acc[6] += bflo(w2.w); acc[7] += bfhi(w2.w);
            }
        }
    }

    // combine the 4 groups
#pragma unroll
    for (int i = 0; i < 8; ++i) {
        acc[i] += __shfl_xor(acc[i], 16, 64);
        acc[i] += __shfl_xor(acc[i], 32, 64);
    }

    if (grp == 0) {
        uint4 o;
        o.x = (unsigned)f2bf(acc[0] * dn) | ((unsigned)f2bf(acc[1] * dn) << 16);
        o.y = (unsigned)f2bf(acc[2] * dn) | ((unsigned)f2bf(acc[3] * dn) << 16);
        o.z = (unsigned)f2bf(acc[4] * dn) | ((unsigned)f2bf(acc[5] * dn) << 16);
        o.w = (unsigned)f2bf(acc[6] * dn) | ((unsigned)f2bf(acc[7] * dn) << 16);
        ((uint4*)(aggb2 + (size_t)n * 64))[sub] = o;
    }
}

// --------------------------- MFMA GEMM + bias + GELU + LayerNorm ------------
// No LDS: B-frags read straight from global Wt (32KB, L1-resident).
// 256 threads = 4 waves; 64 rows/block; no barriers.
__global__ __launch_bounds__(256) void k_gemm_ln(const unsigned short* __restrict__ aggb,
                                                 const unsigned short* __restrict__ Wt,
                                                 const float* __restrict__ bias,
                                                 const float* __restrict__ gamma,
                                                 const float* __restrict__ beta,
                                                 float* __restrict__ outp,
                                                 int N) {
    const int wv   = threadIdx.x >> 6;
    const int lane = threadIdx.x & 63;
    const int g    = lane >> 4;
    const int c    = lane & 15;
    const int r0   = blockIdx.x * 64 + wv * 16;
    if (r0 >= N) return;

    float bc[8], gc[8], bec[8];
#pragma unroll
    for (int ct = 0; ct < 8; ++ct) {
        int col = ct * 16 + c;
        bc[ct]  = bias[col];
        gc[ct]  = gamma[col];
        bec[ct] = beta[col];
    }

    f32x4 acc[8];
#pragma unroll
    for (int ct = 0; ct < 8; ++ct) acc[ct] = (f32x4){0.f, 0.f, 0.f, 0.f};

#pragma unroll
    for (int ks = 0; ks < 4; ++ks) {
        int ar = r0 + c; if (ar >= N) ar = N - 1;
        bf16x8 af = *(const bf16x8*)(aggb + (size_t)ar * H + ks * 32 + g * 8);
#pragma unroll
        for (int ct = 0; ct < 8; ++ct) {
            int j = ct * 16 + c;
            bf16x8 bf = *(const bf16x8*)(Wt + (size_t)j * H + ks * 32 + g * 8);
            acc[ct] = __builtin_amdgcn_mfma_f32_16x16x32_bf16(af, bf, acc[ct], 0, 0, 0);
        }
    }

#pragma unroll
    for (int q = 0; q < 4; ++q) {
        int row = r0 + g * 4 + q;
        float v[8];
        float s = 0.f, sq = 0.f;
#pragma unroll
        for (int ct = 0; ct < 8; ++ct) {
            float t = acc[ct][q] + bc[ct];
            t = 0.5f * t * (1.0f + erff(t * 0.70710678118654752f));
            v[ct] = t;
            s += t;
            sq += t * t;
        }
#pragma unroll
        for (int off = 8; off > 0; off >>= 1) {
            s  += __shfl_xor(s,  off, 64);
            sq += __shfl_xor(sq, off, 64);
        }
        float mu  = s * (1.0f / H);
        float var = sq * (1.0f / H) - mu * mu;
        float rs  = rsqrtf(var + 1e-5f);
        if (row < N) {
            float* op = outp + (size_t)row * H;
#pragma unroll
            for (int ct = 0; ct < 8; ++ct) {
                op[ct * 16 + c] = (v[ct] - mu) * rs * gc[ct] + bec[ct];
            }
        }
    }
}

// ---------------------------------------------------------------- launch ----
extern "C" void kernel_launch(void* const* d_in, const int* in_sizes, int n_in,
                              void* d_out, int out_size, void* d_ws, size_t ws_size,
                              hipStream_t stream) {
    const float* x     = (const float*)d_in[0];
    const int*   ei    = (const int*)d_in[1];
    const float* W     = (const float*)d_in[2];
    const float* b     = (const float*)d_in[3];
    const float* gamma = (const float*)d_in[4];
    const float* beta  = (const float*)d_in[5];
    float* out = (float*)d_out;

    const int N = in_sizes[0] / H;
    const int E = in_sizes[1] / 2;
    const int NBUK = (N + 127) / 128;

    // workspace layout (256 B aligned between arrays)
    char* w = (char*)d_ws;
    auto alloc = [&](size_t bytes) {
        char* p = w;
        w += (bytes + 255) & ~(size_t)255;
        return p;
    };
    float* dinv     = (float*)alloc((size_t)N * 4);
    int*   bcnt_pad = (int*)alloc((size_t)NBUK * 16 * 4);  // 64B-padded counters
    int*   boff     = (int*)alloc((size_t)(NBUK + 1) * 4);
    int*   bcur     = (int*)alloc((size_t)NBUK * 4);
    int*   rowp     = (int*)alloc((size_t)(N + 1) * 4);
    int*   ssrc     = (int*)alloc((size_t)E * 4);
    unsigned short* Wt = (unsigned short*)alloc((size_t)H * H * 2);
    unsigned* aggb2 = (unsigned*)alloc((size_t)N * 64 * 4);

    // d_out staging: first half = xb2 (bf16 x*dinv), upper part = pair records.
    // Both fully consumed before k_gemm_ln overwrites d_out.
    unsigned* xb2  = (unsigned*)d_out;                   // N*64 u32
    unsigned* pair = (unsigned*)d_out + (size_t)N * 64;  // E u32

    k_wt   <<<(H * H) / 256, 256, 0, stream>>>(W, Wt);

    hipMemsetAsync(bcnt_pad, 0, (size_t)NBUK * 16 * 4, stream);
    k_bhist<<<(E + PART_EDGES - 1) / PART_EDGES, 256, 0, stream>>>(ei + E, bcnt_pad, E, NBUK);
    k_bscan<<<1, 1024, 0, stream>>>(bcnt_pad, boff, bcur, rowp, NBUK, N, E);
    k_part <<<(E + PART_EDGES - 1) / PART_EDGES, 256, 0, stream>>>(ei, bcur, pair, E);
    k_sort <<<NBUK, 256, 0, stream>>>(pair, boff, rowp, ssrc, dinv, N);
    k_xb   <<<(N * 32 + 255) / 256, 256, 0, stream>>>(x, dinv, xb2, N);

    k_agg  <<<(N + 3) / 4, 256, 0, stream>>>(xb2, rowp, ssrc, dinv, aggb2, N);

    k_gemm_ln<<<(N + 63) / 64, 256, 0, stream>>>((const unsigned short*)aggb2, Wt,
                                                 b, gamma, beta, out, N);
}

// Round 12
// 161.668 us; speedup vs baseline: 1.2850x; 1.1383x over previous
//
#include <hip/hip_runtime.h>
#include <math.h>

#define H 128
#define PART_EDGES 4096
#define SORT_LDS 4096

typedef __bf16 bf16x8 __attribute__((ext_vector_type(8)));
typedef float f32x4 __attribute__((ext_vector_type(4)));
typedef _Float16 h2 __attribute__((ext_vector_type(2)));

static __device__ __forceinline__ unsigned short f2bf(float f) {
    unsigned u = __float_as_uint(f);
    unsigned r = 0x7fffu + ((u >> 16) & 1u);
    return (unsigned short)((u + r) >> 16);
}
static __device__ __forceinline__ unsigned packh2(float a, float b) {
    h2 h = { (_Float16)a, (_Float16)b };
    return __builtin_bit_cast(unsigned, h);
}
static __device__ __forceinline__ h2 u2h(unsigned w) {
    return __builtin_bit_cast(h2, w);
}

// per-block LDS bucket histogram -> padded global bcnt (stride 16 ints = 64B)
__global__ __launch_bounds__(256) void k_bhist(const int* __restrict__ dst,
                                               int* __restrict__ bcnt_pad,
                                               int E, int NBUK) {
    __shared__ int lh[1024];
    int t = threadIdx.x;
    for (int i = t; i < 1024; i += 256) lh[i] = 0;
    __syncthreads();
    int e0 = blockIdx.x * PART_EDGES;
    int e1 = min(e0 + PART_EDGES, E);
    for (int e = e0 + t; e < e1; e += 256) atomicAdd(&lh[dst[e] >> 7], 1);
    __syncthreads();
    for (int i = t; i < NBUK; i += 256) {
        int h = lh[i];
        if (h) atomicAdd(&bcnt_pad[i * 16], h);
    }
}

// parallel single-block exclusive scan of bucket counts (chunked, carry LDS)
__global__ __launch_bounds__(1024) void k_bscan(const int* __restrict__ bcnt_pad,
                                                int* __restrict__ boff,
                                                int* __restrict__ bcur,
                                                int* __restrict__ rowp,
                                                int NBUK, int N, int E) {
    __shared__ int tmp[1024];
    __shared__ int carry;
    int t = threadIdx.x;
    if (t == 0) carry = 0;
    __syncthreads();
    for (int base = 0; base < NBUK; base += 1024) {
        int i = base + t;
        int v = (i < NBUK) ? bcnt_pad[i * 16] : 0;
        tmp[t] = v;
        __syncthreads();
#pragma unroll
        for (int off = 1; off < 1024; off <<= 1) {
            int a = (t >= off) ? tmp[t - off] : 0;
            __syncthreads();
            tmp[t] += a;
            __syncthreads();
        }
        int excl = carry + tmp[t] - v;
        if (i < NBUK) { boff[i] = excl; bcur[i] = excl; }
        __syncthreads();
        if (t == 1023) carry += tmp[1023];
        __syncthreads();
    }
    if (t == 0) { boff[NBUK] = carry; rowp[N] = E; }
}

// --------------------------------------------------- W transpose to bf16 ----
__global__ void k_wt(const float* __restrict__ W, unsigned short* __restrict__ Wt) {
    int t = blockIdx.x * 256 + threadIdx.x;   // 16384 threads
    int j = t >> 7, k = t & 127;
    Wt[(size_t)j * H + k] = f2bf(W[(size_t)k * H + j]);
}

// ------------------- x pre-scale: word w = fp16 pair (feat 2w, 2w+1) --------
__global__ void k_xb(const float* __restrict__ x, const float* __restrict__ dinv,
                     unsigned* __restrict__ xb2, int N) {
    int t = blockIdx.x * 256 + threadIdx.x;   // N*32 threads
    if (t >= N * 32) return;
    int n = t >> 5;
    float s = dinv[n];
    float4 v = ((const float4*)x)[t];
    uint2 o;
    o.x = packh2(v.x * s, v.y * s);
    o.y = packh2(v.z * s, v.w * s);
    ((uint2*)xb2)[t] = o;
}

// -------------------------------------------- bucket partition of edges -----
// record = src | (dst&127)<<17 ; grouped by bucket (dst>>7)
__global__ __launch_bounds__(256) void k_part(const int* __restrict__ ei,
                                              int* __restrict__ bcur,
                                              unsigned* __restrict__ pair, int E) {
    __shared__ int hist[1024];
    __shared__ int base[1024];
    int t = threadIdx.x;
    for (int i = t; i < 1024; i += 256) hist[i] = 0;
    __syncthreads();
    int e0 = blockIdx.x * PART_EDGES;
    int e1 = min(e0 + PART_EDGES, E);
    for (int e = e0 + t; e < e1; e += 256) {
        int d = ei[E + e];
        atomicAdd(&hist[d >> 7], 1);
    }
    __syncthreads();
    for (int i = t; i < 1024; i += 256) {
        int h = hist[i];
        base[i] = h ? atomicAdd(&bcur[i], h) : 0;
        hist[i] = 0;  // reuse as local cursor
    }
    __syncthreads();
    for (int e = e0 + t; e < e1; e += 256) {
        int s = ei[e];
        int d = ei[E + e];
        int b = d >> 7;
        int r = atomicAdd(&hist[b], 1);
        pair[base[b] + r] = (unsigned)s | ((unsigned)(d & 127) << 17);
    }
}

// --------------- bucket-local counting sort -> ssrc, rowp, dinv -------------
__global__ __launch_bounds__(256) void k_sort(const unsigned* __restrict__ pair,
                                              const int* __restrict__ boff,
                                              int* __restrict__ rowp,
                                              int* __restrict__ ssrc,
                                              float* __restrict__ dinv, int N) {
    __shared__ int hist[128];
    __shared__ int lofs[128];
    __shared__ int cur[128];
    __shared__ int sl[SORT_LDS];
    int b = blockIdx.x;
    int t = threadIdx.x;
    int lo = boff[b], hi = boff[b + 1];
    int cntE = hi - lo;
    if (t < 128) hist[t] = 0;
    __syncthreads();
    for (int i = t; i < cntE; i += 256) {
        unsigned w = pair[lo + i];
        atomicAdd(&hist[w >> 17], 1);
    }
    __syncthreads();
    int n0 = b << 7;
    if (t < 128 && n0 + t < N) dinv[n0 + t] = rsqrtf((float)(hist[t] + 1));
    if (t == 0) {
        int run = 0;
        for (int d = 0; d < 128; ++d) { lofs[d] = run; cur[d] = run; run += hist[d]; }
    }
    __syncthreads();
    if (t < 128 && n0 + t < N) rowp[n0 + t] = lo + lofs[t];
    for (int i = t; i < cntE; i += 256) {
        unsigned w = pair[lo + i];
        int d = w >> 17;
        int s = (int)(w & 0x1FFFF);
        int pos = atomicAdd(&cur[d], 1);
        if (pos < SORT_LDS) sl[pos] = s;
        else ssrc[lo + pos] = s;   // statistically never; correctness fallback
    }
    __syncthreads();
    int lim = min(cntE, SORT_LDS);
    for (int i = t; i < lim; i += 256) ssrc[lo + i] = sl[i];
}

// ------------------------------------------------------ gather aggregate ----
// wave per node; 16 lanes per edge-row (uint4 = 16B/lane = 8 fp16 feats).
// Accumulate in packed fp16 (v_pk_add_f16): 8 VALU ops per 2 gathered rows.
// Full 8-edge iterations mask-free; single predicated tail (exec-masked lanes
// issue no memory requests). ds_bpermute always runs with all 64 lanes.
__global__ __launch_bounds__(256) void k_agg(const unsigned* __restrict__ xb2,
                                             const int* __restrict__ rowp,
                                             const int* __restrict__ ssrc,
                                             const float* __restrict__ dinv,
                                             unsigned* __restrict__ aggb2, int N) {
    int n = blockIdx.x * 4 + (threadIdx.x >> 6);
    if (n >= N) return;
    int lane = threadIdx.x & 63;
    int grp  = lane >> 4;     // 0..3
    int sub  = lane & 15;     // 0..15

    int lo = __builtin_amdgcn_readfirstlane(rowp[n]);
    int hi = __builtin_amdgcn_readfirstlane(rowp[n + 1]);
    float dn = dinv[n];

    h2 acc[4];
#pragma unroll
    for (int i = 0; i < 4; ++i) acc[i] = (h2){ (_Float16)0, (_Float16)0 };

    // self term, added once (group 0 only)
    if (grp == 0) {
        uint4 sw = ((const uint4*)(xb2 + (size_t)n * 64))[sub];
        acc[0] = u2h(sw.x); acc[1] = u2h(sw.y);
        acc[2] = u2h(sw.z); acc[3] = u2h(sw.w);
    }

    for (int base = lo; base < hi; base += 64) {
        int take = hi - base; if (take > 64) take = 64;   // wave-uniform
        int sv = ssrc[base + (lane < take ? lane : take - 1)];

        int nFull = take >> 3;                            // wave-uniform
        for (int it = 0; it < nFull; ++it) {
            int p1 = (it << 3) + grp;
            int p2 = p1 + 4;
            int s1 = __builtin_amdgcn_ds_bpermute(p1 << 2, sv);
            int s2 = __builtin_amdgcn_ds_bpermute(p2 << 2, sv);
            uint4 w1 = ((const uint4*)(xb2 + (size_t)s1 * 64))[sub];
            uint4 w2 = ((const uint4*)(xb2 + (size_t)s2 * 64))[sub];
            acc[0] += u2h(w1.x); acc[1] += u2h(w1.y);
            acc[2] += u2h(w1.z); acc[3] += u2h(w1.w);
            acc[0] += u2h(w2.x); acc[1] += u2h(w2.y);
            acc[2] += u2h(w2.z); acc[3] += u2h(w2.w);
        }
        if (take & 7) {                                    // wave-uniform tail
            int p1 = (nFull << 3) + grp;
            int p2 = p1 + 4;
            int q1 = (p1 < take) ? p1 : take - 1;
            int q2 = (p2 < take) ? p2 : take - 1;
            int s1 = __builtin_amdgcn_ds_bpermute(q1 << 2, sv);
            int s2 = __builtin_amdgcn_ds_bpermute(q2 << 2, sv);
            if (p1 < take) {
                uint4 w1 = ((const uint4*)(xb2 + (size_t)s1 * 64))[sub];
                acc[0] += u2h(w1.x); acc[1] += u2h(w1.y);
                acc[2] += u2h(w1.z); acc[3] += u2h(w1.w);
            }
            if (p2 < take) {
                uint4 w2 = ((const uint4*)(xb2 + (size_t)s2 * 64))[sub];
                acc[0] += u2h(w2.x); acc[1] += u2h(w2.y);
                acc[2] += u2h(w2.z); acc[3] += u2h(w2.w);
            }
        }
    }

    // combine the 4 groups (shfl the packed words)
#pragma unroll
    for (int i = 0; i < 4; ++i) {
        unsigned au = __builtin_bit_cast(unsigned, acc[i]);
        acc[i] += u2h((unsigned)__shfl_xor((int)au, 16, 64));
        au = __builtin_bit_cast(unsigned, acc[i]);
        acc[i] += u2h((unsigned)__shfl_xor((int)au, 32, 64));
    }

    if (grp == 0) {
        uint4 o;
        o.x = (unsigned)f2bf((float)acc[0][0] * dn) | ((unsigned)f2bf((float)acc[0][1] * dn) << 16);
        o.y = (unsigned)f2bf((float)acc[1][0] * dn) | ((unsigned)f2bf((float)acc[1][1] * dn) << 16);
        o.z = (unsigned)f2bf((float)acc[2][0] * dn) | ((unsigned)f2bf((float)acc[2][1] * dn) << 16);
        o.w = (unsigned)f2bf((float)acc[3][0] * dn) | ((unsigned)f2bf((float)acc[3][1] * dn) << 16);
        ((uint4*)(aggb2 + (size_t)n * 64))[sub] = o;
    }
}

// --------------------------- MFMA GEMM + bias + GELU + LayerNorm ------------
// (round-9 measured-good version: Wt staged in 32KB XOR-swizzled LDS)
__global__ __launch_bounds__(512) void k_gemm_ln(const unsigned short* __restrict__ aggb,
                                                 const unsigned short* __restrict__ Wt,
                                                 const float* __restrict__ bias,
                                                 const float* __restrict__ gamma,
                                                 const float* __restrict__ beta,
                                                 float* __restrict__ outp,
                                                 int N) {
    __shared__ unsigned short Ws[H * H];  // 32 KB, XOR-swizzled rows
    {
        const unsigned* src = (const unsigned*)Wt;
#pragma unroll
        for (int i = 0; i < 16; ++i) {
            int idx = threadIdx.x + i * 512;
            unsigned v = src[idx];
            int j = idx >> 6;
            int byte = (idx << 2) ^ ((j & 7) << 4);
            *(unsigned*)((char*)Ws + byte) = v;
        }
    }
    __syncthreads();

    const int wv   = threadIdx.x >> 6;
    const int lane = threadIdx.x & 63;
    const int g    = lane >> 4;
    const int c    = lane & 15;
    const int r0   = blockIdx.x * 128 + wv * 16;
    if (r0 >= N) return;

    float bc[8], gc[8], bec[8];
#pragma unroll
    for (int ct = 0; ct < 8; ++ct) {
        int col = ct * 16 + c;
        bc[ct]  = bias[col];
        gc[ct]  = gamma[col];
        bec[ct] = beta[col];
    }

    f32x4 acc[8];
#pragma unroll
    for (int ct = 0; ct < 8; ++ct) acc[ct] = (f32x4){0.f, 0.f, 0.f, 0.f};

#pragma unroll
    for (int ks = 0; ks < 4; ++ks) {
        int ar = r0 + c; if (ar >= N) ar = N - 1;
        bf16x8 af = *(const bf16x8*)(aggb + (size_t)ar * H + ks * 32 + g * 8);
#pragma unroll
        for (int ct = 0; ct < 8; ++ct) {
            int j = ct * 16 + c;
            int byte = (j * 256 + ks * 64 + g * 16) ^ ((j & 7) << 4);
            bf16x8 bf = *(const bf16x8*)((const char*)Ws + byte);
            acc[ct] = __builtin_amdgcn_mfma_f32_16x16x32_bf16(af, bf, acc[ct], 0, 0, 0);
        }
    }

#pragma unroll
    for (int q = 0; q < 4; ++q) {
        int row = r0 + g * 4 + q;
        float v[8];
        float s = 0.f, sq = 0.f;
#pragma unroll
        for (int ct = 0; ct < 8; ++ct) {
            float t = acc[ct][q] + bc[ct];
            t = 0.5f * t * (1.0f + erff(t * 0.70710678118654752f));
            v[ct] = t;
            s += t;
            sq += t * t;
        }
#pragma unroll
        for (int off = 8; off > 0; off >>= 1) {
            s  += __shfl_xor(s,  off, 64);
            sq += __shfl_xor(sq, off, 64);
        }
        float mu  = s * (1.0f / H);
        float var = sq * (1.0f / H) - mu * mu;
        float rs  = rsqrtf(var + 1e-5f);
        if (row < N) {
            float* op = outp + (size_t)row * H;
#pragma unroll
            for (int ct = 0; ct < 8; ++ct) {
                op[ct * 16 + c] = (v[ct] - mu) * rs * gc[ct] + bec[ct];
            }
        }
    }
}

// ---------------------------------------------------------------- launch ----
extern "C" void kernel_launch(void* const* d_in, const int* in_sizes, int n_in,
                              void* d_out, int out_size, void* d_ws, size_t ws_size,
                              hipStream_t stream) {
    const float* x     = (const float*)d_in[0];
    const int*   ei    = (const int*)d_in[1];
    const float* W     = (const float*)d_in[2];
    const float* b     = (const float*)d_in[3];
    const float* gamma = (const float*)d_in[4];
    const float* beta  = (const float*)d_in[5];
    float* out = (float*)d_out;

    const int N = in_sizes[0] / H;
    const int E = in_sizes[1] / 2;
    const int NBUK = (N + 127) / 128;

    // workspace layout (256 B aligned between arrays)
    char* w = (char*)d_ws;
    auto alloc = [&](size_t bytes) {
        char* p = w;
        w += (bytes + 255) & ~(size_t)255;
        return p;
    };
    float* dinv     = (float*)alloc((size_t)N * 4);
    int*   bcnt_pad = (int*)alloc((size_t)NBUK * 16 * 4);  // 64B-padded counters
    int*   boff     = (int*)alloc((size_t)(NBUK + 1) * 4);
    int*   bcur     = (int*)alloc((size_t)NBUK * 4);
    int*   rowp     = (int*)alloc((size_t)(N + 1) * 4);
    int*   ssrc     = (int*)alloc((size_t)E * 4);
    unsigned short* Wt = (unsigned short*)alloc((size_t)H * H * 2);
    unsigned* aggb2 = (unsigned*)alloc((size_t)N * 64 * 4);

    // d_out staging: first half = xb2 (fp16 x*dinv), upper part = pair records.
    // Both fully consumed before k_gemm_ln overwrites d_out.
    unsigned* xb2  = (unsigned*)d_out;                   // N*64 u32
    unsigned* pair = (unsigned*)d_out + (size_t)N * 64;  // E u32

    k_wt   <<<(H * H) / 256, 256, 0, stream>>>(W, Wt);

    hipMemsetAsync(bcnt_pad, 0, (size_t)NBUK * 16 * 4, stream);
    k_bhist<<<(E + PART_EDGES - 1) / PART_EDGES, 256, 0, stream>>>(ei + E, bcnt_pad, E, NBUK);
    k_bscan<<<1, 1024, 0, stream>>>(bcnt_pad, boff, bcur, rowp, NBUK, N, E);
    k_part <<<(E + PART_EDGES - 1) / PART_EDGES, 256, 0, stream>>>(ei, bcur, pair, E);
    k_sort <<<NBUK, 256, 0, stream>>>(pair, boff, rowp, ssrc, dinv, N);
    k_xb   <<<(N * 32 + 255) / 256, 256, 0, stream>>>(x, dinv, xb2, N);

    k_agg  <<<(N + 3) / 4, 256, 0, stream>>>(xb2, rowp, ssrc, dinv, aggb2, N);

    k_gemm_ln<<<(N + 127) / 128, 512, 0, stream>>>((const unsigned short*)aggb2, Wt,
                                                   b, gamma, beta, out, N);
}

// Round 13
// 152.381 us; speedup vs baseline: 1.3633x; 1.0609x over previous
//
#include <hip/hip_runtime.h>
#include <math.h>

#define H 128
#define PART_EDGES 8192
#define SORT_LDS 4096

typedef __bf16 bf16x8 __attribute__((ext_vector_type(8)));
typedef float f32x4 __attribute__((ext_vector_type(4)));
typedef _Float16 h2 __attribute__((ext_vector_type(2)));
typedef __attribute__((address_space(3))) unsigned lds_u32;
typedef __attribute__((address_space(1))) const unsigned glob_u32;

static __device__ __forceinline__ unsigned short f2bf(float f) {
    unsigned u = __float_as_uint(f);
    unsigned r = 0x7fffu + ((u >> 16) & 1u);
    return (unsigned short)((u + r) >> 16);
}
static __device__ __forceinline__ unsigned packh2(float a, float b) {
    h2 h = { (_Float16)a, (_Float16)b };
    return __builtin_bit_cast(unsigned, h);
}
static __device__ __forceinline__ h2 u2h(unsigned w) {
    return __builtin_bit_cast(h2, w);
}
// exact-enough GELU: erf via A&S 7.1.26 (|err|<=1.5e-7), 1 rcp + 1 exp + 6 fma
static __device__ __forceinline__ float gelu_f(float v) {
    float z  = v * 0.70710678118654752f;
    float az = fabsf(z);
    float t  = __frcp_rn(1.0f + 0.3275911f * az);
    float p  = t * (0.254829592f + t * (-0.284496736f + t * (1.421413741f +
               t * (-1.453152027f + t * 1.061405429f))));
    float e  = p * __expf(-az * az);
    float erf = 1.0f - e;
    erf = (z < 0.0f) ? -erf : erf;
    return 0.5f * v * (1.0f + erf);
}

// per-block LDS bucket histogram -> padded global bcnt (stride 16 ints = 64B)
__global__ __launch_bounds__(512) void k_bhist(const int* __restrict__ dst,
                                               int* __restrict__ bcnt_pad,
                                               int E, int NBUK) {
    __shared__ int lh[1024];
    int t = threadIdx.x;
    for (int i = t; i < 1024; i += 512) lh[i] = 0;
    __syncthreads();
    int e0 = blockIdx.x * PART_EDGES;
    int e1 = min(e0 + PART_EDGES, E);
    for (int e = e0 + t; e < e1; e += 512) atomicAdd(&lh[dst[e] >> 7], 1);
    __syncthreads();
    for (int i = t; i < NBUK; i += 512) {
        int h = lh[i];
        if (h) atomicAdd(&bcnt_pad[i * 16], h);
    }
}

// parallel single-block exclusive scan of bucket counts (chunked, carry LDS)
__global__ __launch_bounds__(1024) void k_bscan(const int* __restrict__ bcnt_pad,
                                                int* __restrict__ boff,
                                                int* __restrict__ bcur,
                                                int* __restrict__ rowp,
                                                int NBUK, int N, int E) {
    __shared__ int tmp[1024];
    __shared__ int carry;
    int t = threadIdx.x;
    if (t == 0) carry = 0;
    __syncthreads();
    for (int base = 0; base < NBUK; base += 1024) {
        int i = base + t;
        int v = (i < NBUK) ? bcnt_pad[i * 16] : 0;
        tmp[t] = v;
        __syncthreads();
#pragma unroll
        for (int off = 1; off < 1024; off <<= 1) {
            int a = (t >= off) ? tmp[t - off] : 0;
            __syncthreads();
            tmp[t] += a;
            __syncthreads();
        }
        int excl = carry + tmp[t] - v;
        if (i < NBUK) { boff[i] = excl; bcur[i] = excl; }
        __syncthreads();
        if (t == 1023) carry += tmp[1023];
        __syncthreads();
    }
    if (t == 0) { boff[NBUK] = carry; rowp[N] = E; }
}

// ---------------- W transpose to bf16, PRE-SWIZZLED global layout -----------
// element (j,k) stored at byte (j*256 + 2k) ^ ((j&7)<<4) so a LINEAR
// global->LDS copy yields the swizzled LDS image (rule: swizzle source, not dest)
__global__ void k_wt(const float* __restrict__ W, unsigned short* __restrict__ Wsz) {
    int t = blockIdx.x * 256 + threadIdx.x;   // 16384 threads
    int j = t >> 7, k = t & 127;
    unsigned byte = (unsigned)(j * 256 + 2 * k) ^ (((unsigned)j & 7u) << 4);
    *(unsigned short*)((char*)Wsz + byte) = f2bf(W[(size_t)k * H + j]);
}

// ------------------- x pre-scale: word w = fp16 pair (feat 2w, 2w+1) --------
__global__ void k_xb(const float* __restrict__ x, const float* __restrict__ dinv,
                     unsigned* __restrict__ xb2, int N) {
    int t = blockIdx.x * 256 + threadIdx.x;   // N*32 threads
    if (t >= N * 32) return;
    int n = t >> 5;
    float s = dinv[n];
    float4 v = ((const float4*)x)[t];
    uint2 o;
    o.x = packh2(v.x * s, v.y * s);
    o.y = packh2(v.z * s, v.w * s);
    ((uint2*)xb2)[t] = o;
}

// -------------------------------------------- bucket partition of edges -----
// record = src | (dst&127)<<17 ; grouped by bucket (dst>>7)
__global__ __launch_bounds__(512) void k_part(const int* __restrict__ ei,
                                              int* __restrict__ bcur,
                                              unsigned* __restrict__ pair, int E) {
    __shared__ int hist[1024];
    __shared__ int base[1024];
    int t = threadIdx.x;
    for (int i = t; i < 1024; i += 512) hist[i] = 0;
    __syncthreads();
    int e0 = blockIdx.x * PART_EDGES;
    int e1 = min(e0 + PART_EDGES, E);
    for (int e = e0 + t; e < e1; e += 512) {
        int d = ei[E + e];
        atomicAdd(&hist[d >> 7], 1);
    }
    __syncthreads();
    for (int i = t; i < 1024; i += 512) {
        int h = hist[i];
        base[i] = h ? atomicAdd(&bcur[i], h) : 0;
        hist[i] = 0;  // reuse as local cursor
    }
    __syncthreads();
    for (int e = e0 + t; e < e1; e += 512) {
        int s = ei[e];
        int d = ei[E + e];
        int b = d >> 7;
        int r = atomicAdd(&hist[b], 1);
        pair[base[b] + r] = (unsigned)s | ((unsigned)(d & 127) << 17);
    }
}

// --------------- bucket-local counting sort -> ssrc, rowp, dinv -------------
__global__ __launch_bounds__(256) void k_sort(const unsigned* __restrict__ pair,
                                              const int* __restrict__ boff,
                                              int* __restrict__ rowp,
                                              int* __restrict__ ssrc,
                                              float* __restrict__ dinv, int N) {
    __shared__ int hist[128];
    __shared__ int lofs[128];
    __shared__ int cur[128];
    __shared__ int sl[SORT_LDS];
    int b = blockIdx.x;
    int t = threadIdx.x;
    int lo = boff[b], hi = boff[b + 1];
    int cntE = hi - lo;
    if (t < 128) hist[t] = 0;
    __syncthreads();
    for (int i = t; i < cntE; i += 256) {
        unsigned w = pair[lo + i];
        atomicAdd(&hist[w >> 17], 1);
    }
    __syncthreads();
    int n0 = b << 7;
    if (t < 128 && n0 + t < N) dinv[n0 + t] = rsqrtf((float)(hist[t] + 1));
    if (t == 0) {
        int run = 0;
        for (int d = 0; d < 128; ++d) { lofs[d] = run; cur[d] = run; run += hist[d]; }
    }
    __syncthreads();
    if (t < 128 && n0 + t < N) rowp[n0 + t] = lo + lofs[t];
    for (int i = t; i < cntE; i += 256) {
        unsigned w = pair[lo + i];
        int d = w >> 17;
        int s = (int)(w & 0x1FFFF);
        int pos = atomicAdd(&cur[d], 1);
        if (pos < SORT_LDS) sl[pos] = s;
        else ssrc[lo + pos] = s;   // statistically never; correctness fallback
    }
    __syncthreads();
    int lim = min(cntE, SORT_LDS);
    for (int i = t; i < lim; i += 256) ssrc[lo + i] = sl[i];
}

// ------------------------------------------------------ gather aggregate ----
__global__ __launch_bounds__(256) void k_agg(const unsigned* __restrict__ xb2,
                                             const int* __restrict__ rowp,
                                             const int* __restrict__ ssrc,
                                             const float* __restrict__ dinv,
                                             unsigned* __restrict__ aggb2, int N) {
    int n = blockIdx.x * 4 + (threadIdx.x >> 6);
    if (n >= N) return;
    int lane = threadIdx.x & 63;
    int grp  = lane >> 4;     // 0..3
    int sub  = lane & 15;     // 0..15

    int lo = __builtin_amdgcn_readfirstlane(rowp[n]);
    int hi = __builtin_amdgcn_readfirstlane(rowp[n + 1]);
    float dn = dinv[n];

    h2 acc[4];
#pragma unroll
    for (int i = 0; i < 4; ++i) acc[i] = (h2){ (_Float16)0, (_Float16)0 };

    if (grp == 0) {
        uint4 sw = ((const uint4*)(xb2 + (size_t)n * 64))[sub];
        acc[0] = u2h(sw.x); acc[1] = u2h(sw.y);
        acc[2] = u2h(sw.z); acc[3] = u2h(sw.w);
    }

    for (int base = lo; base < hi; base += 64) {
        int take = hi - base; if (take > 64) take = 64;   // wave-uniform
        int sv = ssrc[base + (lane < take ? lane : take - 1)];

        int nFull = take >> 3;                            // wave-uniform
        for (int it = 0; it < nFull; ++it) {
            int p1 = (it << 3) + grp;
            int p2 = p1 + 4;
            int s1 = __builtin_amdgcn_ds_bpermute(p1 << 2, sv);
            int s2 = __builtin_amdgcn_ds_bpermute(p2 << 2, sv);
            uint4 w1 = ((const uint4*)(xb2 + (size_t)s1 * 64))[sub];
            uint4 w2 = ((const uint4*)(xb2 + (size_t)s2 * 64))[sub];
            acc[0] += u2h(w1.x); acc[1] += u2h(w1.y);
            acc[2] += u2h(w1.z); acc[3] += u2h(w1.w);
            acc[0] += u2h(w2.x); acc[1] += u2h(w2.y);
            acc[2] += u2h(w2.z); acc[3] += u2h(w2.w);
        }
        if (take & 7) {                                    // wave-uniform tail
            int p1 = (nFull << 3) + grp;
            int p2 = p1 + 4;
            int q1 = (p1 < take) ? p1 : take - 1;
            int q2 = (p2 < take) ? p2 : take - 1;
            int s1 = __builtin_amdgcn_ds_bpermute(q1 << 2, sv);
            int s2 = __builtin_amdgcn_ds_bpermute(q2 << 2, sv);
            if (p1 < take) {
                uint4 w1 = ((const uint4*)(xb2 + (size_t)s1 * 64))[sub];
                acc[0] += u2h(w1.x); acc[1] += u2h(w1.y);
                acc[2] += u2h(w1.z); acc[3] += u2h(w1.w);
            }
            if (p2 < take) {
                uint4 w2 = ((const uint4*)(xb2 + (size_t)s2 * 64))[sub];
                acc[0] += u2h(w2.x); acc[1] += u2h(w2.y);
                acc[2] += u2h(w2.z); acc[3] += u2h(w2.w);
            }
        }
    }

#pragma unroll
    for (int i = 0; i < 4; ++i) {
        unsigned au = __builtin_bit_cast(unsigned, acc[i]);
        acc[i] += u2h((unsigned)__shfl_xor((int)au, 16, 64));
        au = __builtin_bit_cast(unsigned, acc[i]);
        acc[i] += u2h((unsigned)__shfl_xor((int)au, 32, 64));
    }

    if (grp == 0) {
        uint4 o;
        o.x = (unsigned)f2bf((float)acc[0][0] * dn) | ((unsigned)f2bf((float)acc[0][1] * dn) << 16);
        o.y = (unsigned)f2bf((float)acc[1][0] * dn) | ((unsigned)f2bf((float)acc[1][1] * dn) << 16);
        o.z = (unsigned)f2bf((float)acc[2][0] * dn) | ((unsigned)f2bf((float)acc[2][1] * dn) << 16);
        o.w = (unsigned)f2bf((float)acc[3][0] * dn) | ((unsigned)f2bf((float)acc[3][1] * dn) << 16);
        ((uint4*)(aggb2 + (size_t)n * 64))[sub] = o;
    }
}

// --------------------------- MFMA GEMM + bias + GELU + LayerNorm ------------
// A-loads hoisted before the staging barrier; W staged via global_load_lds
// (linear copy of the pre-swizzled Wsz); fast-erf GELU epilogue.
__global__ __launch_bounds__(512) void k_gemm_ln(const unsigned short* __restrict__ aggb,
                                                 const unsigned short* __restrict__ Wsz,
                                                 const float* __restrict__ bias,
                                                 const float* __restrict__ gamma,
                                                 const float* __restrict__ beta,
                                                 float* __restrict__ outp,
                                                 int N) {
    __shared__ unsigned short Ws[H * H];  // 32 KB (holds swizzled image)

    const int wv   = threadIdx.x >> 6;
    const int lane = threadIdx.x & 63;
    const int g    = lane >> 4;
    const int c    = lane & 15;
    const int r0   = blockIdx.x * 128 + wv * 16;

    // A-frags first: overlap HBM latency with W staging
    int ar = r0 + c; if (ar >= N) ar = N - 1;
    bf16x8 af[4];
#pragma unroll
    for (int ks = 0; ks < 4; ++ks)
        af[ks] = *(const bf16x8*)(aggb + (size_t)ar * H + ks * 32 + g * 8);

    // linear global->LDS copy (dest = wave base + lane*16 automatically)
#pragma unroll
    for (int it = 0; it < 4; ++it) {
        int off = it * 8192 + wv * 1024;
        __builtin_amdgcn_global_load_lds(
            (glob_u32*)((const char*)Wsz + off + lane * 16),
            (lds_u32*)((char*)Ws + off), 16, 0, 0);
    }
    __syncthreads();

    if (r0 < N) {
        float bc[8], gc[8], bec[8];
#pragma unroll
        for (int ct = 0; ct < 8; ++ct) {
            int col = ct * 16 + c;
            bc[ct]  = bias[col];
            gc[ct]  = gamma[col];
            bec[ct] = beta[col];
        }

        f32x4 acc[8];
#pragma unroll
        for (int ct = 0; ct < 8; ++ct) acc[ct] = (f32x4){0.f, 0.f, 0.f, 0.f};

#pragma unroll
        for (int ks = 0; ks < 4; ++ks) {
#pragma unroll
            for (int ct = 0; ct < 8; ++ct) {
                int j = ct * 16 + c;
                int byte = (j * 256 + ks * 64 + g * 16) ^ ((j & 7) << 4);
                bf16x8 bf = *(const bf16x8*)((const char*)Ws + byte);
                acc[ct] = __builtin_amdgcn_mfma_f32_16x16x32_bf16(af[ks], bf, acc[ct], 0, 0, 0);
            }
        }

#pragma unroll
        for (int q = 0; q < 4; ++q) {
            int row = r0 + g * 4 + q;
            float v[8];
            float s = 0.f, sq = 0.f;
#pragma unroll
            for (int ct = 0; ct < 8; ++ct) {
                float t = gelu_f(acc[ct][q] + bc[ct]);
                v[ct] = t;
                s += t;
                sq += t * t;
            }
#pragma unroll
            for (int off = 8; off > 0; off >>= 1) {
                s  += __shfl_xor(s,  off, 64);
                sq += __shfl_xor(sq, off, 64);
            }
            float mu  = s * (1.0f / H);
            float var = sq * (1.0f / H) - mu * mu;
            float rs  = rsqrtf(var + 1e-5f);
            if (row < N) {
                float* op = outp + (size_t)row * H;
#pragma unroll
                for (int ct = 0; ct < 8; ++ct) {
                    op[ct * 16 + c] = (v[ct] - mu) * rs * gc[ct] + bec[ct];
                }
            }
        }
    }
}

// ---------------------------------------------------------------- launch ----
extern "C" void kernel_launch(void* const* d_in, const int* in_sizes, int n_in,
                              void* d_out, int out_size, void* d_ws, size_t ws_size,
                              hipStream_t stream) {
    const float* x     = (const float*)d_in[0];
    const int*   ei    = (const int*)d_in[1];
    const float* W     = (const float*)d_in[2];
    const float* b     = (const float*)d_in[3];
    const float* gamma = (const float*)d_in[4];
    const float* beta  = (const float*)d_in[5];
    float* out = (float*)d_out;

    const int N = in_sizes[0] / H;
    const int E = in_sizes[1] / 2;
    const int NBUK = (N + 127) / 128;

    // workspace layout (256 B aligned between arrays)
    char* w = (char*)d_ws;
    auto alloc = [&](size_t bytes) {
        char* p = w;
        w += (bytes + 255) & ~(size_t)255;
        return p;
    };
    float* dinv     = (float*)alloc((size_t)N * 4);
    int*   bcnt_pad = (int*)alloc((size_t)NBUK * 16 * 4);  // 64B-padded counters
    int*   boff     = (int*)alloc((size_t)(NBUK + 1) * 4);
    int*   bcur     = (int*)alloc((size_t)NBUK * 4);
    int*   rowp     = (int*)alloc((size_t)(N + 1) * 4);
    int*   ssrc     = (int*)alloc((size_t)E * 4);
    unsigned short* Wsz = (unsigned short*)alloc((size_t)H * H * 2);
    unsigned* aggb2 = (unsigned*)alloc((size_t)N * 64 * 4);

    // d_out staging: first half = xb2 (fp16 x*dinv), upper part = pair records.
    // Both fully consumed before k_gemm_ln overwrites d_out.
    unsigned* xb2  = (unsigned*)d_out;                   // N*64 u32
    unsigned* pair = (unsigned*)d_out + (size_t)N * 64;  // E u32

    k_wt   <<<(H * H) / 256, 256, 0, stream>>>(W, Wsz);

    hipMemsetAsync(bcnt_pad, 0, (size_t)NBUK * 16 * 4, stream);
    k_bhist<<<(E + PART_EDGES - 1) / PART_EDGES, 512, 0, stream>>>(ei + E, bcnt_pad, E, NBUK);
    k_bscan<<<1, 1024, 0, stream>>>(bcnt_pad, boff, bcur, rowp, NBUK, N, E);
    k_part <<<(E + PART_EDGES - 1) / PART_EDGES, 512, 0, stream>>>(ei, bcur, pair, E);
    k_sort <<<NBUK, 256, 0, stream>>>(pair, boff, rowp, ssrc, dinv, N);
    k_xb   <<<(N * 32 + 255) / 256, 256, 0, stream>>>(x, dinv, xb2, N);

    k_agg  <<<(N + 3) / 4, 256, 0, stream>>>(xb2, rowp, ssrc, dinv, aggb2, N);

    k_gemm_ln<<<(N + 127) / 128, 512, 0, stream>>>((const unsigned short*)aggb2, Wsz,
                                                   b, gamma, beta, out, N);
}